// Round 2
// baseline (197.519 us; speedup 1.0000x reference)
//
#include <hip/hip_runtime.h>

// EOQLinear: int4-quantized GEMV.
//   out[n] = sum_b scales[n,b] * sum_{q in block b} w_int[n,q] * x[q]
// packed_w[n,j] is an int32 in [0,256): low nibble -> k=2j, high nibble -> k=2j+1,
// both offset by -8.
//
// DTYPE NOTE (round-1 post-mortem): the harness stages the reference's float16
// tensors as FLOAT32 (bf16 reads of x produced NaN from float mantissa halves;
// real-fp16-as-bf16 would have been finite garbage). So x, scales, out are f32.
//
// Layout: one 64-lane wave per output row, 4 rows per 256-thread block
// (2048 blocks, 8 blocks/CU -> full 32-wave occupancy, zero LDS).
// Weights: 16B int4 loads, 1 KiB contiguous per wave-instruction (the only
// HBM-significant stream, 128 MiB). x: 32 KB, L1/L2-resident, read as 2x float4
// per lane-iter. Factored per-quant-block scale applied once per 4-int chunk
// (4 consecutive packed ints always lie in one 64-int quant block).

#define WAVES_PER_BLOCK 4

__global__ __launch_bounds__(256, 4)
void eoq_gemv_kernel(const float* __restrict__ x,
                     const int* __restrict__ packed_w,
                     const float* __restrict__ scales,
                     float* __restrict__ out,
                     int N, int halfK, int blocksPerRow, int qhalfShift)
{
    const int lane = threadIdx.x & 63;
    const int wave = threadIdx.x >> 6;
    const int row  = blockIdx.x * WAVES_PER_BLOCK + wave;
    if (row >= N) return;

    const int4*   __restrict__ w4p =
        reinterpret_cast<const int4*>(packed_w + (size_t)row * halfK);
    const float4* __restrict__ x4p = reinterpret_cast<const float4*>(x);
    const float*  __restrict__ srow = scales + (size_t)row * blocksPerRow;

    float acc = 0.f;
    const int iters = halfK >> 8;   // halfK / (64 lanes * 4 ints); 16 for K=8192

    #pragma unroll 4
    for (int it = 0; it < iters; ++it) {
        const int j4 = it * 64 + lane;       // int4 index within the row
        const int4   w4 = w4p[j4];           // 4 packed ints = 8 weights
        const float4 xa = x4p[2 * j4];       // x[8*j4   .. 8*j4+3]
        const float4 xb = x4p[2 * j4 + 1];   // x[8*j4+4 .. 8*j4+7]
        const float s = srow[(j4 << 2) >> qhalfShift];

        float xv[8];
        *(float4*)&xv[0] = xa;
        *(float4*)&xv[4] = xb;

        float part = 0.f;
        #pragma unroll
        for (int i = 0; i < 4; ++i) {
            const unsigned w = ((const unsigned*)&w4)[i];
            // nibbles: w < 256, so (w>>4) needs no mask
            const float wlo = (float)(int)(w & 0xFu) - 8.f;  // even k
            const float whi = (float)(int)(w >> 4)   - 8.f;  // odd  k
            part = fmaf(wlo, xv[2 * i],     part);
            part = fmaf(whi, xv[2 * i + 1], part);
        }
        acc = fmaf(s, part, acc);
    }

    // wave-64 reduction
    #pragma unroll
    for (int off = 32; off > 0; off >>= 1)
        acc += __shfl_down(acc, off, 64);

    if (lane == 0) out[row] = acc;
}

extern "C" void kernel_launch(void* const* d_in, const int* in_sizes, int n_in,
                              void* d_out, int out_size, void* d_ws, size_t ws_size,
                              hipStream_t stream) {
    const float* x      = (const float*)d_in[0];
    const int*   pw     = (const int*)d_in[1];
    const float* scales = (const float*)d_in[2];
    float*       out    = (float*)d_out;

    const int K     = in_sizes[0];         // 8192
    const int halfK = K >> 1;              // 4096
    const int N     = in_sizes[1] / halfK; // 8192
    const int blocksPerRow = in_sizes[2] / N;    // K/QB = 64
    // packed ints per quant block = QB/2; shift = log2(QB/2) (QB=128 -> 6)
    const int qhalf = halfK / blocksPerRow;
    int qhalfShift = 0;
    while ((1 << qhalfShift) < qhalf) ++qhalfShift;

    dim3 grid((N + WAVES_PER_BLOCK - 1) / WAVES_PER_BLOCK), block(256);
    eoq_gemv_kernel<<<grid, block, 0, stream>>>(x, pw, scales, out,
                                                N, halfK, blocksPerRow, qhalfShift);
}